// Round 17
// baseline (170.919 us; speedup 1.0000x reference)
//
#include <hip/hip_runtime.h>
#include <hip/hip_bf16.h>

#define NB 8
#define C1 512
#define C2 256
#define HWSZ 4096
#define BN_EPS 1e-5f
#define P2 264   // As2 pitch in ushorts
#define PA 72    // As pitch in ushorts (64 cols + pad)

typedef __hip_bfloat16 bf16;
typedef __hip_bfloat162 bf162;
typedef __attribute__((ext_vector_type(8))) short short8v;
typedef __attribute__((ext_vector_type(4))) float f32x4;

static __device__ inline float us2f(unsigned short u) {
  union { unsigned u32; float f; } c; c.u32 = ((unsigned)u) << 16; return c.f;
}

static __device__ inline unsigned short f2bf(float f) {
  union { bf16 h; unsigned short u; } c;
  c.h = __float2bfloat16(f);
  return c.u;
}

static __device__ inline uint2 pack4(float a, float b, float c, float d) {
  union { uint2 u; bf162 h[2]; } pk;
  pk.h[0] = __float22bfloat162_rn(make_float2(a, b));
  pk.h[1] = __float22bfloat162_rn(make_float2(c, d));
  return pk.u;
}

// XOR block-swizzles (8-ushort blocks, row-dependent mask; bijective per row,
// preserves 16B alignment).
#define SWB(m_, c_)  (((((c_) >> 3) ^ (((m_) >> 3) & 7)) << 3) + ((c_) & 7))   // As cols [0,64)
#define SWA2(m_, c_) (((((c_) >> 3) ^ (((m_) >> 3) & 7)) << 3) + ((c_) & 7))   // As2 cols [0,256)

#define SBARQ() asm volatile("s_waitcnt lgkmcnt(0)\n\ts_barrier" ::: "memory")
#define SBAR()  asm volatile("s_barrier" ::: "memory")
#define LGKM0() asm volatile("s_waitcnt lgkmcnt(0)" ::: "memory")

// ---------------------------------------------------------------------------
// K0: weight prep + flow zeroing.  (unchanged)
// ---------------------------------------------------------------------------
__global__ __launch_bounds__(256) void k0_prep(
    const float* __restrict__ wch, const float* __restrict__ wcc1,
    const float* __restrict__ wcc2,
    unsigned short* __restrict__ wchB, unsigned short* __restrict__ wcc1B,
    float* __restrict__ wr, float* __restrict__ flow) {
  const int t = blockIdx.x * 256 + threadIdx.x;
  if (t < 262144) {
    const int which = t >> 17;
    const int r = t & 131071;
    const int i = r & 7;
    const int lane = (r >> 3) & 63;
    const int ntile = (r >> 9) & 15;
    const int kstep = r >> 13;
    const int ci = kstep * 32 + (lane >> 4) * 8 + i;
    const int co = ntile * 16 + (lane & 15);
    const float* s = which ? wcc1 : wch;
    unsigned short* d = which ? wcc1B : wchB;
    d[r] = f2bf(s[co * 512 + ci]);
  } else if (t < 262144 + 9216) {
    const int r = t - 262144;
    const int f = r / 2304;
    const int rr = r % 2304;
    const int ci = rr / 9;
    const int tt = rr % 9;
    wr[ci * 36 + (tt / 3) * 12 + (tt % 3) * 4 + f] = wcc2[r];
  } else if (t < 262144 + 9216 + 131072) {
    flow[t - 262144 - 9216] = 0.f;
  }
}

// ---------------------------------------------------------------------------
// K12 v8: BK=64 — phase A in 8 staged iterations, phase B's x2 half in 4.
// Halves barrier-event count; doubles MFMA per barrier. Rest as v7.
// ---------------------------------------------------------------------------
__global__ __launch_bounds__(512) void k12_fused(
    const float* __restrict__ x1, const float* __restrict__ x2,
    const unsigned short* __restrict__ wchB, const unsigned short* __restrict__ wcc1B,
    const float* __restrict__ bch,
    const float* __restrict__ gamma, const float* __restrict__ beta,
    const float* __restrict__ mean, const float* __restrict__ var,
    const float* __restrict__ wr,
    unsigned short* __restrict__ x1c_nhwc, unsigned short* __restrict__ x2_nhwc,
    float* __restrict__ flow) {
  __shared__ unsigned short As[64 * PA];     // staging tile [m][k<64]
  __shared__ unsigned short As2[64 * P2];    // phase A output / conv input
  const int tid = threadIdx.x;
  const int lane = tid & 63;
  const int wv = tid >> 6;
  const int lrow = lane & 15;
  const int lgrp = lane >> 4;

  const int m0g = blockIdx.x * 64;
  const int n = m0g >> 12;
  const int hw0 = m0g & 4095;
  const int h = hw0 >> 6;

  f32x4 acc[4][2];
#pragma unroll
  for (int mt = 0; mt < 4; ++mt)
#pragma unroll
    for (int nt = 0; nt < 2; ++nt) acc[mt][nt] = (f32x4){0.f, 0.f, 0.f, 0.f};

  // ================= phase A: maxpool + conv1x1(w_change), BK=64 ===========
  const int pmi = tid & 31;
  const int ms = pmi * 2;
  const int ch0 = (tid >> 5) * 4;    // 0,4,...,60

  const float* x1p = x1 + (size_t)n * C1 * 16384 + (size_t)(2 * h) * 128 + 2 * ms;

  float4 ta[4], tb[4];   // in-flight raw: 4 channels x (top,bottom)
#define LOADA(K0_) do { \
    _Pragma("unroll") \
    for (int c_ = 0; c_ < 4; ++c_) { \
      const float* p_ = x1p + (size_t)((K0_) + ch0 + c_) * 16384; \
      ta[c_] = *(const float4*)p_; tb[c_] = *(const float4*)(p_ + 128); \
    } \
  } while (0)
#define POOLA(U0_, U1_) do { \
    U0_ = pack4(fmaxf(fmaxf(ta[0].x, ta[0].y), fmaxf(tb[0].x, tb[0].y)), \
                fmaxf(fmaxf(ta[1].x, ta[1].y), fmaxf(tb[1].x, tb[1].y)), \
                fmaxf(fmaxf(ta[2].x, ta[2].y), fmaxf(tb[2].x, tb[2].y)), \
                fmaxf(fmaxf(ta[3].x, ta[3].y), fmaxf(tb[3].x, tb[3].y))); \
    U1_ = pack4(fmaxf(fmaxf(ta[0].z, ta[0].w), fmaxf(tb[0].z, tb[0].w)), \
                fmaxf(fmaxf(ta[1].z, ta[1].w), fmaxf(tb[1].z, tb[1].w)), \
                fmaxf(fmaxf(ta[2].z, ta[2].w), fmaxf(tb[2].z, tb[2].w)), \
                fmaxf(fmaxf(ta[3].z, ta[3].w), fmaxf(tb[3].z, tb[3].w))); \
  } while (0)

  uint2 uA0, uA1;
  LOADA(0);
  POOLA(uA0, uA1);
  LOADA(64);               // step 1 in flight

  for (int ks = 0; ks < 8; ++ks) {
    SBARQ();                                  // all waves' As reads drained
    *(uint2*)&As[ms * PA + SWB(ms, ch0)] = uA0;
    *(uint2*)&As[(ms + 1) * PA + SWB(ms + 1, ch0)] = uA1;
    LGKM0();
    SBAR();                                   // writes visible

    if (ks < 7) {
      uint2 uN0, uN1;
      POOLA(uN0, uN1);                        // pool step ks+1
      if (ks < 6) LOADA((ks + 2) * 64);       // issue step ks+2
      uA0 = uN0; uA1 = uN1;
    }

#pragma unroll
    for (int kk = 0; kk < 2; ++kk) {
      short8v a[4];
#pragma unroll
      for (int mt = 0; mt < 4; ++mt) {
        const int m = mt * 16 + lrow;
        a[mt] = *(const short8v*)&As[m * PA + SWB(m, kk * 32 + lgrp * 8)];
      }
      const int kstep = ks * 2 + kk;
#pragma unroll
      for (int nt = 0; nt < 2; ++nt) {
        const int ntile = wv * 2 + nt;
        const short8v b = *(const short8v*)&wchB[(size_t)((kstep * 16 + ntile) * 64 + lane) * 8];
#pragma unroll
        for (int mt = 0; mt < 4; ++mt)
          acc[mt][nt] = __builtin_amdgcn_mfma_f32_16x16x32_bf16(a[mt], b, acc[mt][nt], 0, 0, 0);
      }
    }
  }

  // ---- prefetch x2 steps 0,1 for phase B's staged half (hidden under As2-half)
  const int chB2 = tid >> 3;        // 0..63
  const int mq2 = (tid & 7) * 8;    // 0..56
  float4 s0a, s0b, s1a, s1b;
#define LOADB(K0_, A_, B_) do { \
    const float* p_ = &x2[((size_t)(n * C2 + (K0_) + chB2)) * HWSZ + hw0 + mq2]; \
    A_ = *(const float4*)p_; B_ = *(const float4*)(p_ + 4); \
  } while (0)
  LOADB(0, s0a, s0b);
  LOADB(64, s1a, s1b);

  // ---- epilogue A: +bias -> bf16 into As2
#pragma unroll
  for (int nt = 0; nt < 2; ++nt) {
    const int co = (wv * 2 + nt) * 16 + lrow;
    const float bias = bch[co];
#pragma unroll
    for (int mt = 0; mt < 4; ++mt) {
      const f32x4 v = acc[mt][nt];
      const uint2 pk = pack4(v.x + bias, v.y + bias, v.z + bias, v.w + bias);
      const int mb = mt * 16 + lgrp * 4;
      As2[(mb + 0) * P2 + SWA2(mb + 0, co)] = (unsigned short)(pk.x & 0xffffu);
      As2[(mb + 1) * P2 + SWA2(mb + 1, co)] = (unsigned short)(pk.x >> 16);
      As2[(mb + 2) * P2 + SWA2(mb + 2, co)] = (unsigned short)(pk.y & 0xffffu);
      As2[(mb + 3) * P2 + SWA2(mb + 3, co)] = (unsigned short)(pk.y >> 16);
      acc[mt][nt] = (f32x4){0.f, 0.f, 0.f, 0.f};
    }
  }
  LGKM0();
  SBAR();   // As2 complete

  // ---- NHWC x1c emission (16B reads = exactly one swizzle block)
  {
    const int mm = tid >> 3;
    const int cg = (tid & 7) * 32;
    const size_t ob = ((size_t)(m0g + mm)) * 256 + cg;
#pragma unroll
    for (int k = 0; k < 4; ++k) {
      const uint4 v = *(const uint4*)&As2[mm * P2 + SWA2(mm, cg + k * 8)];
      *(uint4*)&x1c_nhwc[ob + k * 8] = v;
    }
  }

  // ================= phase B: concat + conv1x1(w_cc1) + BN + ReLU ==========
  // first half: A-operand = phase A result from As2 (no barriers)
#pragma unroll
  for (int ks = 0; ks < 8; ++ks) {
    short8v a[4];
#pragma unroll
    for (int mt = 0; mt < 4; ++mt) {
      const int m = mt * 16 + lrow;
      a[mt] = *(const short8v*)&As2[m * P2 + SWA2(m, ks * 32 + lgrp * 8)];
    }
#pragma unroll
    for (int nt = 0; nt < 2; ++nt) {
      const int ntile = wv * 2 + nt;
      const short8v b = *(const short8v*)&wcc1B[(size_t)((ks * 16 + ntile) * 64 + lane) * 8];
#pragma unroll
      for (int mt = 0; mt < 4; ++mt)
        acc[mt][nt] = __builtin_amdgcn_mfma_f32_16x16x32_bf16(a[mt], b, acc[mt][nt], 0, 0, 0);
    }
  }

  // second half: x2 channels, BK=64, 4 fully-unrolled iterations, ping-pong.
#define STAGEB(J_, SA_, SB_) do { \
    unsigned short us_[8]; \
    us_[0] = f2bf(SA_.x); us_[1] = f2bf(SA_.y); us_[2] = f2bf(SA_.z); us_[3] = f2bf(SA_.w); \
    us_[4] = f2bf(SB_.x); us_[5] = f2bf(SB_.y); us_[6] = f2bf(SB_.z); us_[7] = f2bf(SB_.w); \
    SBARQ(); \
    _Pragma("unroll") \
    for (int i_ = 0; i_ < 8; ++i_) \
      As[(mq2 + i_) * PA + SWB(mq2 + i_, chB2)] = us_[i_]; \
    LGKM0(); \
    SBAR(); \
    /* NHWC x2 emission for this 64-channel slab */ \
    { \
      const int m_ = tid >> 3; \
      const int c8_ = (tid & 7) * 8; \
      const uint4 v_ = *(const uint4*)&As[m_ * PA + SWB(m_, c8_)]; \
      *(uint4*)&x2_nhwc[((size_t)(m0g + m_)) * 256 + (J_) * 64 + c8_] = v_; \
    } \
  } while (0)

#define MFMAB(J_) do { \
    _Pragma("unroll") \
    for (int kk = 0; kk < 2; ++kk) { \
      short8v a_[4]; \
      _Pragma("unroll") \
      for (int mt = 0; mt < 4; ++mt) { \
        const int m_ = mt * 16 + lrow; \
        a_[mt] = *(const short8v*)&As[m_ * PA + SWB(m_, kk * 32 + lgrp * 8)]; \
      } \
      const int kstep_ = 8 + (J_) * 2 + kk; \
      _Pragma("unroll") \
      for (int nt = 0; nt < 2; ++nt) { \
        const int ntile_ = wv * 2 + nt; \
        const short8v b_ = *(const short8v*)&wcc1B[(size_t)((kstep_ * 16 + ntile_) * 64 + lane) * 8]; \
        _Pragma("unroll") \
        for (int mt = 0; mt < 4; ++mt) \
          acc[mt][nt] = __builtin_amdgcn_mfma_f32_16x16x32_bf16(a_[mt], b_, acc[mt][nt], 0, 0, 0); \
      } \
    } \
  } while (0)

  STAGEB(0, s0a, s0b); LOADB(128, s0a, s0b); MFMAB(0);
  STAGEB(1, s1a, s1b); LOADB(192, s1a, s1b); MFMAB(1);
  STAGEB(2, s0a, s0b); MFMAB(2);
  STAGEB(3, s1a, s1b); MFMAB(3);

  // ---- epilogue B: BN + ReLU -> bf16 into As2 (xbn tile stays in LDS)
  SBARQ();
#pragma unroll
  for (int nt = 0; nt < 2; ++nt) {
    const int co = (wv * 2 + nt) * 16 + lrow;
    const float sc = gamma[co] * rsqrtf(var[co] + BN_EPS);
    const float sh = beta[co] - mean[co] * sc;
#pragma unroll
    for (int mt = 0; mt < 4; ++mt) {
      const f32x4 vv = acc[mt][nt];
      const uint2 pk = pack4(fmaxf(vv.x * sc + sh, 0.f), fmaxf(vv.y * sc + sh, 0.f),
                             fmaxf(vv.z * sc + sh, 0.f), fmaxf(vv.w * sc + sh, 0.f));
      const int mb = mt * 16 + lgrp * 4;
      As2[(mb + 0) * P2 + SWA2(mb + 0, co)] = (unsigned short)(pk.x & 0xffffu);
      As2[(mb + 1) * P2 + SWA2(mb + 1, co)] = (unsigned short)(pk.x >> 16);
      As2[(mb + 2) * P2 + SWA2(mb + 2, co)] = (unsigned short)(pk.y & 0xffffu);
      As2[(mb + 3) * P2 + SWA2(mb + 3, co)] = (unsigned short)(pk.y >> 16);
    }
  }
  LGKM0();
  SBAR();   // As2 (= xbn row tile) visible to all

  // ---- phase C: conv3x3 row-partials -> atomicAdd into flow
  {
    const int xp = tid & 63;
    const int fh = tid >> 6;
    const int f = fh & 3;
    const int half = fh >> 2;
    float pm = 0.f, pz = 0.f, pp = 0.f;
    for (int ci = half * 128; ci < half * 128 + 128; ci += 2) {
      const float* w0 = wr + ci * 36 + f;
#pragma unroll
      for (int dx = 0; dx < 3; ++dx) {
        const int xs = xp + dx - 1;
        if ((unsigned)xs >= 64u) continue;
        const unsigned vv = *(const unsigned*)&As2[xs * P2 + SWA2(xs, ci)];
        const float v0 = us2f((unsigned short)(vv & 0xffffu));
        const float v1 = us2f((unsigned short)(vv >> 16));
        const float* wa = w0 + dx * 4;
        const float* wb = wa + 36;
        pm = fmaf(v0, wa[24], fmaf(v1, wb[24], pm));
        pz = fmaf(v0, wa[12], fmaf(v1, wb[12], pz));
        pp = fmaf(v0, wa[0],  fmaf(v1, wb[0],  pp));
      }
    }
    float* fb = flow + ((size_t)(n * 4 + f)) * HWSZ + xp;
    if (h >= 1)  atomicAdd(fb + (h - 1) * 64, pm);
    atomicAdd(fb + h * 64, pz);
    if (h <= 62) atomicAdd(fb + (h + 1) * 64, pp);
  }
#undef LOADA
#undef POOLA
#undef LOADB
#undef STAGEB
#undef MFMAB
}

// ---------------------------------------------------------------------------
// K4: sampler only (unchanged)
// ---------------------------------------------------------------------------
__global__ __launch_bounds__(1024) void k4_sample(
    const float* __restrict__ flow,
    const unsigned short* __restrict__ x1c_nhwc,
    const unsigned short* __restrict__ x2_nhwc,
    float* __restrict__ out) {
  __shared__ float outT[256][65];
  __shared__ float flr[4][64];
  __shared__ int   toff[8][64];
  __shared__ float twt[8][64];

  const int tid = threadIdx.x;
  const int n = blockIdx.x >> 6;
  const int h = blockIdx.x & 63;
  const int wl = tid & 63;
  const int q = tid >> 6;

  if (tid < 256) {
    flr[tid >> 6][tid & 63] =
        flow[((size_t)(n * 4 + (tid >> 6))) * HWSZ + h * 64 + (tid & 63)];
  }
  __syncthreads();

  if (tid < 64) {
    const float fxv[2] = {flr[0][tid], flr[2][tid]};
    const float fyv[2] = {flr[1][tid], flr[3][tid]};
#pragma unroll
    for (int s = 0; s < 2; ++s) {
      const float ix = (float)tid + fxv[s], iy = (float)h + fyv[s];
      const float x0f = floorf(ix), y0f = floorf(iy);
      const float fx = ix - x0f, fy = iy - y0f;
      const int x0 = (int)x0f, y0 = (int)y0f, x1i = x0 + 1, y1i = y0 + 1;
      const float vx0 = (x0 >= 0 && x0 < 64) ? 1.f : 0.f;
      const float vx1 = (x1i >= 0 && x1i < 64) ? 1.f : 0.f;
      const float vy0 = (y0 >= 0 && y0 < 64) ? 1.f : 0.f;
      const float vy1 = (y1i >= 0 && y1i < 64) ? 1.f : 0.f;
      const int cx0 = min(max(x0, 0), 63), cx1 = min(max(x1i, 0), 63);
      const int cy0 = min(max(y0, 0), 63), cy1 = min(max(y1i, 0), 63);
      toff[s * 4 + 0][tid] = cy0 * 64 + cx0;
      toff[s * 4 + 1][tid] = cy0 * 64 + cx1;
      toff[s * 4 + 2][tid] = cy1 * 64 + cx0;
      toff[s * 4 + 3][tid] = cy1 * 64 + cx1;
      twt[s * 4 + 0][tid] = (1.f - fx) * (1.f - fy) * vx0 * vy0;
      twt[s * 4 + 1][tid] = fx * (1.f - fy) * vx1 * vy0;
      twt[s * 4 + 2][tid] = (1.f - fx) * fy * vx0 * vy1;
      twt[s * 4 + 3][tid] = fx * fy * vx1 * vy1;
    }
  }
  __syncthreads();

  {
    const unsigned short* pb1 = x1c_nhwc + (size_t)n * HWSZ * 256 + wl * 4;
    const unsigned short* pb2 = x2_nhwc + (size_t)n * HWSZ * 256 + wl * 4;
#pragma unroll
    for (int pp = 0; pp < 4; ++pp) {
      const int p = q * 4 + pp;
      float u0 = 0.f, u1 = 0.f, u2 = 0.f, u3 = 0.f;
#pragma unroll
      for (int t = 0; t < 8; ++t) {
        const int off = toff[t][p];
        const float wt = twt[t][p];
        const unsigned short* rp = (t < 4 ? pb1 : pb2) + (size_t)off * 256;
        const uint2 v = *(const uint2*)rp;
        u0 = fmaf(wt, us2f((unsigned short)(v.x & 0xffffu)), u0);
        u1 = fmaf(wt, us2f((unsigned short)(v.x >> 16)), u1);
        u2 = fmaf(wt, us2f((unsigned short)(v.y & 0xffffu)), u2);
        u3 = fmaf(wt, us2f((unsigned short)(v.y >> 16)), u3);
      }
      outT[wl * 4 + 0][p] = u0;
      outT[wl * 4 + 1][p] = u1;
      outT[wl * 4 + 2][p] = u2;
      outT[wl * 4 + 3][p] = u3;
    }
  }
  __syncthreads();

  {
    const int p = tid & 63;
    const int cg = (tid >> 6) * 16;
    const size_t ob = ((size_t)(n * C2 + cg)) * HWSZ + h * 64 + p;
#pragma unroll
    for (int j = 0; j < 16; ++j) {
      out[ob + (size_t)j * HWSZ] = outT[cg + j][p];
    }
  }
}

// ---------------------------------------------------------------------------
extern "C" void kernel_launch(void* const* d_in, const int* in_sizes, int n_in,
                              void* d_out, int out_size, void* d_ws, size_t ws_size,
                              hipStream_t stream) {
  const float* x1      = (const float*)d_in[0];
  const float* x2      = (const float*)d_in[1];
  const float* w_change= (const float*)d_in[2];
  const float* b_change= (const float*)d_in[3];
  const float* w_cc1   = (const float*)d_in[4];
  const float* bn_gamma= (const float*)d_in[5];
  const float* bn_beta = (const float*)d_in[6];
  const float* bn_mean = (const float*)d_in[7];
  const float* bn_var  = (const float*)d_in[8];
  const float* w_cc2   = (const float*)d_in[9];
  float* out = (float*)d_out;

  unsigned short* x1c_nhwc = (unsigned short*)d_ws;
  unsigned short* x2_nhwc  = (unsigned short*)((char*)d_ws + (16u << 20));
  float*          flow     = (float*)((char*)d_ws + (32u << 20));
  unsigned short* wchB     = (unsigned short*)((char*)d_ws + (32u << 20) + (512u << 10));
  unsigned short* wcc1B    = (unsigned short*)((char*)d_ws + (32u << 20) + (768u << 10));
  float*          wr       = (float*)((char*)d_ws + (33u << 20));

  k0_prep<<<1572, 256, 0, stream>>>(w_change, w_cc1, w_cc2, wchB, wcc1B, wr, flow);
  k12_fused<<<512, 512, 0, stream>>>(x1, x2, wchB, wcc1B, b_change,
                                     bn_gamma, bn_beta, bn_mean, bn_var, wr,
                                     x1c_nhwc, x2_nhwc, flow);
  k4_sample<<<512, 1024, 0, stream>>>(flow, x1c_nhwc, x2_nhwc, out);
}

// Round 18
// 134.816 us; speedup vs baseline: 1.2678x; 1.2678x over previous
//
#include <hip/hip_runtime.h>
#include <hip/hip_bf16.h>

#define NB 8
#define C1 512
#define C2 256
#define HWSZ 4096
#define BN_EPS 1e-5f
#define P2 264   // As2 pitch in ushorts

typedef __hip_bfloat16 bf16;
typedef __hip_bfloat162 bf162;
typedef __attribute__((ext_vector_type(8))) short short8v;
typedef __attribute__((ext_vector_type(4))) float f32x4;

static __device__ inline float us2f(unsigned short u) {
  union { unsigned u32; float f; } c; c.u32 = ((unsigned)u) << 16; return c.f;
}

static __device__ inline unsigned short f2bf(float f) {
  union { bf16 h; unsigned short u; } c;
  c.h = __float2bfloat16(f);
  return c.u;
}

static __device__ inline uint2 pack4(float a, float b, float c, float d) {
  union { uint2 u; bf162 h[2]; } pk;
  pk.h[0] = __float22bfloat162_rn(make_float2(a, b));
  pk.h[1] = __float22bfloat162_rn(make_float2(c, d));
  return pk.u;
}

// XOR block-swizzles (8-ushort blocks, row-dependent mask; bijective per row).
#define SWA(m_, c_)  (((((c_) >> 3) ^ (((m_) >> 3) & 3)) << 3) + ((c_) & 7))   // As cols [0,32)
#define SWA2(m_, c_) (((((c_) >> 3) ^ (((m_) >> 3) & 7)) << 3) + ((c_) & 7))   // As2 cols [0,256)

#define SBARQ() asm volatile("s_waitcnt lgkmcnt(0)\n\ts_barrier" ::: "memory")
#define SBAR()  asm volatile("s_barrier" ::: "memory")
#define LGKM0() asm volatile("s_waitcnt lgkmcnt(0)" ::: "memory")

// ---------------------------------------------------------------------------
// K0: weight prep + flow zeroing.  (unchanged)
// ---------------------------------------------------------------------------
__global__ __launch_bounds__(256) void k0_prep(
    const float* __restrict__ wch, const float* __restrict__ wcc1,
    const float* __restrict__ wcc2,
    unsigned short* __restrict__ wchB, unsigned short* __restrict__ wcc1B,
    float* __restrict__ wr, float* __restrict__ flow) {
  const int t = blockIdx.x * 256 + threadIdx.x;
  if (t < 262144) {
    const int which = t >> 17;
    const int r = t & 131071;
    const int i = r & 7;
    const int lane = (r >> 3) & 63;
    const int ntile = (r >> 9) & 15;
    const int kstep = r >> 13;
    const int ci = kstep * 32 + (lane >> 4) * 8 + i;
    const int co = ntile * 16 + (lane & 15);
    const float* s = which ? wcc1 : wch;
    unsigned short* d = which ? wcc1B : wchB;
    d[r] = f2bf(s[co * 512 + ci]);
  } else if (t < 262144 + 9216) {
    const int r = t - 262144;
    const int f = r / 2304;
    const int rr = r % 2304;
    const int ci = rr / 9;
    const int tt = rr % 9;
    wr[ci * 36 + (tt / 3) * 12 + (tt % 3) * 4 + f] = wcc2[r];
  } else if (t < 262144 + 9216 + 131072) {
    flow[t - 262144 - 9216] = 0.f;
  }
}

// ---------------------------------------------------------------------------
// K12 v9: v7 structure (BK=32) at 1024 threads / 16 waves per block.
// Wave wv owns ntile=wv (acc[4][1]); 2 blocks/CU x 16 waves = full occupancy.
// ---------------------------------------------------------------------------
__global__ __launch_bounds__(1024) void k12_fused(
    const float* __restrict__ x1, const float* __restrict__ x2,
    const unsigned short* __restrict__ wchB, const unsigned short* __restrict__ wcc1B,
    const float* __restrict__ bch,
    const float* __restrict__ gamma, const float* __restrict__ beta,
    const float* __restrict__ mean, const float* __restrict__ var,
    const float* __restrict__ wr,
    unsigned short* __restrict__ x1c_nhwc, unsigned short* __restrict__ x2_nhwc,
    float* __restrict__ flow) {
  __shared__ unsigned short As[64 * 40];     // staging tile [m][k<32]
  __shared__ unsigned short As2[64 * P2];    // phase A output / conv input
  const int tid = threadIdx.x;
  const int lane = tid & 63;
  const int wv = tid >> 6;          // 0..15 = ntile
  const int lrow = lane & 15;
  const int lgrp = lane >> 4;

  const int m0g = blockIdx.x * 64;
  const int n = m0g >> 12;
  const int hw0 = m0g & 4095;
  const int h = hw0 >> 6;

  f32x4 acc[4];
#pragma unroll
  for (int mt = 0; mt < 4; ++mt) acc[mt] = (f32x4){0.f, 0.f, 0.f, 0.f};

  // ================= phase A: maxpool + conv1x1(w_change), BK=32 ===========
  // staging: thread = (m-pair, channel): 32 m-pairs x 32 ch = 1024 threads
  const int pmi = tid & 31;
  const int ms = pmi * 2;           // 0..62
  const int chA = tid >> 5;         // 0..31

  const float* x1p = x1 + (size_t)n * C1 * 16384 + (size_t)(2 * h) * 128 + 2 * ms;

  float4 t0, b0;
#define LOADA(K0_) do { \
    const float* p_ = x1p + (size_t)((K0_) + chA) * 16384; \
    t0 = *(const float4*)p_;  b0 = *(const float4*)(p_ + 128); \
  } while (0)
#define POOLA(U0_, U1_) do { \
    U0_ = f2bf(fmaxf(fmaxf(t0.x, t0.y), fmaxf(b0.x, b0.y))); \
    U1_ = f2bf(fmaxf(fmaxf(t0.z, t0.w), fmaxf(b0.z, b0.w))); \
  } while (0)

  unsigned short uA0, uA1;
  LOADA(0);
  POOLA(uA0, uA1);
  LOADA(32);               // ks=1 in flight

  for (int ks = 0; ks < 16; ++ks) {
    SBARQ();                                  // all waves' As reads drained
    As[ms * 40 + SWA(ms, chA)] = uA0;
    As[(ms + 1) * 40 + SWA(ms + 1, chA)] = uA1;
    LGKM0();
    SBAR();                                   // writes visible

    if (ks < 15) {
      unsigned short uN0, uN1;
      POOLA(uN0, uN1);
      if (ks < 14) LOADA((ks + 2) * 32);
      uA0 = uN0; uA1 = uN1;
    }

    short8v a[4];
#pragma unroll
    for (int mt = 0; mt < 4; ++mt) {
      const int m = mt * 16 + lrow;
      a[mt] = *(const short8v*)&As[m * 40 + SWA(m, lgrp * 8)];
    }
    const short8v b = *(const short8v*)&wchB[(size_t)((ks * 16 + wv) * 64 + lane) * 8];
#pragma unroll
    for (int mt = 0; mt < 4; ++mt)
      acc[mt] = __builtin_amdgcn_mfma_f32_16x16x32_bf16(a[mt], b, acc[mt], 0, 0, 0);
  }

  // ---- prefetch x2 for phase B (channels 0..31), float2 per thread
  const int chB = tid >> 5;         // 0..31
  const int mqB = (tid & 31) * 2;   // 0..62
  float2 cf0 = *(const float2*)&x2[((size_t)(n * C2 + chB)) * HWSZ + hw0 + mqB];
  float2 cf1 = *(const float2*)&x2[((size_t)(n * C2 + 32 + chB)) * HWSZ + hw0 + mqB];

  // ---- epilogue A: +bias -> bf16 into As2
  {
    const int co = wv * 16 + lrow;
    const float bias = bch[co];
#pragma unroll
    for (int mt = 0; mt < 4; ++mt) {
      const f32x4 v = acc[mt];
      const uint2 pk = pack4(v.x + bias, v.y + bias, v.z + bias, v.w + bias);
      const int mb = mt * 16 + lgrp * 4;
      As2[(mb + 0) * P2 + SWA2(mb + 0, co)] = (unsigned short)(pk.x & 0xffffu);
      As2[(mb + 1) * P2 + SWA2(mb + 1, co)] = (unsigned short)(pk.x >> 16);
      As2[(mb + 2) * P2 + SWA2(mb + 2, co)] = (unsigned short)(pk.y & 0xffffu);
      As2[(mb + 3) * P2 + SWA2(mb + 3, co)] = (unsigned short)(pk.y >> 16);
      acc[mt] = (f32x4){0.f, 0.f, 0.f, 0.f};
    }
  }
  LGKM0();
  SBAR();   // As2 complete

  // ---- NHWC x1c emission: thread (mm = tid>>4, cg = (tid&15)*16): 32B each
  {
    const int mm = tid >> 4;
    const int cg = (tid & 15) * 16;
    const size_t ob = ((size_t)(m0g + mm)) * 256 + cg;
#pragma unroll
    for (int k = 0; k < 2; ++k) {
      const uint4 v = *(const uint4*)&As2[mm * P2 + SWA2(mm, cg + k * 8)];
      *(uint4*)&x1c_nhwc[ob + k * 8] = v;
    }
  }

  // ================= phase B: concat + conv1x1(w_cc1) + BN + ReLU ==========
  // ks 0..7: A-operand = phase A result from As2 (no barriers)
#pragma unroll
  for (int ks = 0; ks < 8; ++ks) {
    short8v a[4];
#pragma unroll
    for (int mt = 0; mt < 4; ++mt) {
      const int m = mt * 16 + lrow;
      a[mt] = *(const short8v*)&As2[m * P2 + SWA2(m, ks * 32 + lgrp * 8)];
    }
    const short8v b = *(const short8v*)&wcc1B[(size_t)((ks * 16 + wv) * 64 + lane) * 8];
#pragma unroll
    for (int mt = 0; mt < 4; ++mt)
      acc[mt] = __builtin_amdgcn_mfma_f32_16x16x32_bf16(a[mt], b, acc[mt], 0, 0, 0);
  }

  // ks 8..15: A-operand = x2, staged via As; double-buffered register prefetch
  for (int ks = 8; ks < 16; ++ks) {
    const unsigned short p0 = f2bf(cf0.x);
    const unsigned short p1 = f2bf(cf0.y);
    cf0 = cf1;
    if (ks < 14) {
      cf1 = *(const float2*)&x2[((size_t)(n * C2 + (ks - 6) * 32 + chB)) * HWSZ + hw0 + mqB];
    }
    SBARQ();
    As[(mqB + 0) * 40 + SWA(mqB + 0, chB)] = p0;
    As[(mqB + 1) * 40 + SWA(mqB + 1, chB)] = p1;
    LGKM0();
    SBAR();

    // NHWC x2 emission: thread (m = tid>>4, c2 = (tid&15)*2): one uint
    {
      const int m = tid >> 4;
      const int c2 = (tid & 15) * 2;
      const unsigned v = *(const unsigned*)&As[m * 40 + SWA(m, c2)];
      *(unsigned*)&x2_nhwc[((size_t)(m0g + m)) * 256 + (ks - 8) * 32 + c2] = v;
    }

    short8v a[4];
#pragma unroll
    for (int mt = 0; mt < 4; ++mt) {
      const int m = mt * 16 + lrow;
      a[mt] = *(const short8v*)&As[m * 40 + SWA(m, lgrp * 8)];
    }
    const short8v b = *(const short8v*)&wcc1B[(size_t)((ks * 16 + wv) * 64 + lane) * 8];
#pragma unroll
    for (int mt = 0; mt < 4; ++mt)
      acc[mt] = __builtin_amdgcn_mfma_f32_16x16x32_bf16(a[mt], b, acc[mt], 0, 0, 0);
  }

  // ---- epilogue B: BN + ReLU -> bf16 into As2
  SBARQ();
  {
    const int co = wv * 16 + lrow;
    const float sc = gamma[co] * rsqrtf(var[co] + BN_EPS);
    const float sh = beta[co] - mean[co] * sc;
#pragma unroll
    for (int mt = 0; mt < 4; ++mt) {
      const f32x4 vv = acc[mt];
      const uint2 pk = pack4(fmaxf(vv.x * sc + sh, 0.f), fmaxf(vv.y * sc + sh, 0.f),
                             fmaxf(vv.z * sc + sh, 0.f), fmaxf(vv.w * sc + sh, 0.f));
      const int mb = mt * 16 + lgrp * 4;
      As2[(mb + 0) * P2 + SWA2(mb + 0, co)] = (unsigned short)(pk.x & 0xffffu);
      As2[(mb + 1) * P2 + SWA2(mb + 1, co)] = (unsigned short)(pk.x >> 16);
      As2[(mb + 2) * P2 + SWA2(mb + 2, co)] = (unsigned short)(pk.y & 0xffffu);
      As2[(mb + 3) * P2 + SWA2(mb + 3, co)] = (unsigned short)(pk.y >> 16);
    }
  }
  LGKM0();
  SBAR();   // As2 (= xbn row tile) visible to all

  // ---- phase C: conv3x3 row-partials -> atomicAdd into flow
  // thread = (xp = tid&63, fh = tid>>6, 0..15): f = fh&3, quarter = fh>>2.
  {
    const int xp = tid & 63;
    const int fh = tid >> 6;
    const int f = fh & 3;
    const int quarter = fh >> 2;
    float pm = 0.f, pz = 0.f, pp = 0.f;
    for (int ci = quarter * 64; ci < quarter * 64 + 64; ci += 2) {
      const float* w0 = wr + ci * 36 + f;
#pragma unroll
      for (int dx = 0; dx < 3; ++dx) {
        const int xs = xp + dx - 1;
        if ((unsigned)xs >= 64u) continue;
        const unsigned vv = *(const unsigned*)&As2[xs * P2 + SWA2(xs, ci)];
        const float v0 = us2f((unsigned short)(vv & 0xffffu));
        const float v1 = us2f((unsigned short)(vv >> 16));
        const float* wa = w0 + dx * 4;
        const float* wb = wa + 36;
        pm = fmaf(v0, wa[24], fmaf(v1, wb[24], pm));
        pz = fmaf(v0, wa[12], fmaf(v1, wb[12], pz));
        pp = fmaf(v0, wa[0],  fmaf(v1, wb[0],  pp));
      }
    }
    float* fb = flow + ((size_t)(n * 4 + f)) * HWSZ + xp;
    if (h >= 1)  atomicAdd(fb + (h - 1) * 64, pm);
    atomicAdd(fb + h * 64, pz);
    if (h <= 62) atomicAdd(fb + (h + 1) * 64, pp);
  }
#undef LOADA
#undef POOLA
}

// ---------------------------------------------------------------------------
// K4: sampler only (unchanged)
// ---------------------------------------------------------------------------
__global__ __launch_bounds__(1024) void k4_sample(
    const float* __restrict__ flow,
    const unsigned short* __restrict__ x1c_nhwc,
    const unsigned short* __restrict__ x2_nhwc,
    float* __restrict__ out) {
  __shared__ float outT[256][65];
  __shared__ float flr[4][64];
  __shared__ int   toff[8][64];
  __shared__ float twt[8][64];

  const int tid = threadIdx.x;
  const int n = blockIdx.x >> 6;
  const int h = blockIdx.x & 63;
  const int wl = tid & 63;
  const int q = tid >> 6;

  if (tid < 256) {
    flr[tid >> 6][tid & 63] =
        flow[((size_t)(n * 4 + (tid >> 6))) * HWSZ + h * 64 + (tid & 63)];
  }
  __syncthreads();

  if (tid < 64) {
    const float fxv[2] = {flr[0][tid], flr[2][tid]};
    const float fyv[2] = {flr[1][tid], flr[3][tid]};
#pragma unroll
    for (int s = 0; s < 2; ++s) {
      const float ix = (float)tid + fxv[s], iy = (float)h + fyv[s];
      const float x0f = floorf(ix), y0f = floorf(iy);
      const float fx = ix - x0f, fy = iy - y0f;
      const int x0 = (int)x0f, y0 = (int)y0f, x1i = x0 + 1, y1i = y0 + 1;
      const float vx0 = (x0 >= 0 && x0 < 64) ? 1.f : 0.f;
      const float vx1 = (x1i >= 0 && x1i < 64) ? 1.f : 0.f;
      const float vy0 = (y0 >= 0 && y0 < 64) ? 1.f : 0.f;
      const float vy1 = (y1i >= 0 && y1i < 64) ? 1.f : 0.f;
      const int cx0 = min(max(x0, 0), 63), cx1 = min(max(x1i, 0), 63);
      const int cy0 = min(max(y0, 0), 63), cy1 = min(max(y1i, 0), 63);
      toff[s * 4 + 0][tid] = cy0 * 64 + cx0;
      toff[s * 4 + 1][tid] = cy0 * 64 + cx1;
      toff[s * 4 + 2][tid] = cy1 * 64 + cx0;
      toff[s * 4 + 3][tid] = cy1 * 64 + cx1;
      twt[s * 4 + 0][tid] = (1.f - fx) * (1.f - fy) * vx0 * vy0;
      twt[s * 4 + 1][tid] = fx * (1.f - fy) * vx1 * vy0;
      twt[s * 4 + 2][tid] = (1.f - fx) * fy * vx0 * vy1;
      twt[s * 4 + 3][tid] = fx * fy * vx1 * vy1;
    }
  }
  __syncthreads();

  {
    const unsigned short* pb1 = x1c_nhwc + (size_t)n * HWSZ * 256 + wl * 4;
    const unsigned short* pb2 = x2_nhwc + (size_t)n * HWSZ * 256 + wl * 4;
#pragma unroll
    for (int pp = 0; pp < 4; ++pp) {
      const int p = q * 4 + pp;
      float u0 = 0.f, u1 = 0.f, u2 = 0.f, u3 = 0.f;
#pragma unroll
      for (int t = 0; t < 8; ++t) {
        const int off = toff[t][p];
        const float wt = twt[t][p];
        const unsigned short* rp = (t < 4 ? pb1 : pb2) + (size_t)off * 256;
        const uint2 v = *(const uint2*)rp;
        u0 = fmaf(wt, us2f((unsigned short)(v.x & 0xffffu)), u0);
        u1 = fmaf(wt, us2f((unsigned short)(v.x >> 16)), u1);
        u2 = fmaf(wt, us2f((unsigned short)(v.y & 0xffffu)), u2);
        u3 = fmaf(wt, us2f((unsigned short)(v.y >> 16)), u3);
      }
      outT[wl * 4 + 0][p] = u0;
      outT[wl * 4 + 1][p] = u1;
      outT[wl * 4 + 2][p] = u2;
      outT[wl * 4 + 3][p] = u3;
    }
  }
  __syncthreads();

  {
    const int p = tid & 63;
    const int cg = (tid >> 6) * 16;
    const size_t ob = ((size_t)(n * C2 + cg)) * HWSZ + h * 64 + p;
#pragma unroll
    for (int j = 0; j < 16; ++j) {
      out[ob + (size_t)j * HWSZ] = outT[cg + j][p];
    }
  }
}

// ---------------------------------------------------------------------------
extern "C" void kernel_launch(void* const* d_in, const int* in_sizes, int n_in,
                              void* d_out, int out_size, void* d_ws, size_t ws_size,
                              hipStream_t stream) {
  const float* x1      = (const float*)d_in[0];
  const float* x2      = (const float*)d_in[1];
  const float* w_change= (const float*)d_in[2];
  const float* b_change= (const float*)d_in[3];
  const float* w_cc1   = (const float*)d_in[4];
  const float* bn_gamma= (const float*)d_in[5];
  const float* bn_beta = (const float*)d_in[6];
  const float* bn_mean = (const float*)d_in[7];
  const float* bn_var  = (const float*)d_in[8];
  const float* w_cc2   = (const float*)d_in[9];
  float* out = (float*)d_out;

  unsigned short* x1c_nhwc = (unsigned short*)d_ws;
  unsigned short* x2_nhwc  = (unsigned short*)((char*)d_ws + (16u << 20));
  float*          flow     = (float*)((char*)d_ws + (32u << 20));
  unsigned short* wchB     = (unsigned short*)((char*)d_ws + (32u << 20) + (512u << 10));
  unsigned short* wcc1B    = (unsigned short*)((char*)d_ws + (32u << 20) + (768u << 10));
  float*          wr       = (float*)((char*)d_ws + (33u << 20));

  k0_prep<<<1572, 256, 0, stream>>>(w_change, w_cc1, w_cc2, wchB, wcc1B, wr, flow);
  k12_fused<<<512, 1024, 0, stream>>>(x1, x2, wchB, wcc1B, b_change,
                                      bn_gamma, bn_beta, bn_mean, bn_var, wr,
                                      x1c_nhwc, x2_nhwc, flow);
  k4_sample<<<512, 1024, 0, stream>>>(flow, x1c_nhwc, x2_nhwc, out);
}